// Round 4
// baseline (3208.738 us; speedup 1.0000x reference)
//
#include <hip/hip_runtime.h>

// ---------------------------------------------------------------------------
// EPSparseMoeBlock: B=2, L=2048, D=2048, E=8, K=2, I=768, IS=4096, T=4096
// bf16 MFMA GEMMs (fp32 accum), fp32 router, sparse top-2 dispatch.
// R9: 1-wave 64x128 barrier-free + XCD decode + setprio -> 755us
//   (gateup 233 @ Mfma 37%, FETCH 556MB). Hidden cost: down_shared streams
//   act_s 16x (N=128 panels); gateup streams h 20x/XCD.
// R10: N-per-block 128 -> 256 (acc[4][16], 256 AGPRs, 40KB LDS, 4 blk/CU):
//   halves streamed-matrix passes (act_s 16->8, h-slices 20->10/XCD),
//   FLOP/L2-byte 42.7->56.9, 128 MFMA per vmcnt wait. down_shared gets
//   1-panel-per-XCD decode (2MB wsd panel L2-resident, act_s 1 pass/XCD).
// 5 launches: cast -> router(+h cast) -> gateup_all -> down_shared -> down_expert
// ---------------------------------------------------------------------------

#define T_TOK 4096
#define DIM   2048
#define NEXP  8
#define IEXP  768
#define ISHR  4096

typedef __attribute__((ext_vector_type(8))) short bf16x8_t;  // 8 bf16 (4 VGPR)
typedef __attribute__((ext_vector_type(4))) float f32x4_t;   // MFMA acc

__device__ __forceinline__ unsigned short f2bf(float f) {
    unsigned int u = __float_as_uint(f);
    u += 0x7fffu + ((u >> 16) & 1u);   // round-to-nearest-even
    return (unsigned short)(u >> 16);
}

// async global->LDS, 16 B per lane; lds dest is wave-uniform base,
// HW scatters lane i at base + i*16 (m97/m104 semantics).
__device__ __forceinline__ void gl2lds16(const unsigned short* g, unsigned short* l) {
    __builtin_amdgcn_global_load_lds(
        (const __attribute__((address_space(1))) unsigned int*)g,
        (__attribute__((address_space(3))) unsigned int*)l, 16, 0, 0);
}

// --- fused weight casts fp32 -> bf16 (5 tensors) + cnt zero ----------------
#define C0 6291456   // gup   (8*1536*2048)/4
#define C1 9437184   // + dnp (8*2048*768)/4
#define C2 11534336  // + sgw (4096*2048)/4
#define C3 13631488  // + suw
#define C4 15728640  // + sdw
__global__ __launch_bounds__(256) void fused_cast_kernel(
    const float* __restrict__ s0, const float* __restrict__ s1,
    const float* __restrict__ s2, const float* __restrict__ s3,
    const float* __restrict__ s4,
    unsigned short* __restrict__ d0, unsigned short* __restrict__ d1,
    unsigned short* __restrict__ d2, unsigned short* __restrict__ d3,
    unsigned short* __restrict__ d4, int* __restrict__ cnt) {
    if (blockIdx.x == 0 && threadIdx.x < NEXP) cnt[threadIdx.x] = 0;
    int i = blockIdx.x * 256 + threadIdx.x;
    const float* src; unsigned short* dst; int base;
    if      (i < C0) { src = s0; dst = d0; base = 0;  }
    else if (i < C1) { src = s1; dst = d1; base = C0; }
    else if (i < C2) { src = s2; dst = d2; base = C1; }
    else if (i < C3) { src = s3; dst = d3; base = C2; }
    else             { src = s4; dst = d4; base = C3; }
    int j = i - base;
    float4 v = ((const float4*)src)[j];
    short4 r;
    r.x = (short)f2bf(v.x); r.y = (short)f2bf(v.y);
    r.z = (short)f2bf(v.z); r.w = (short)f2bf(v.w);
    ((short4*)dst)[j] = r;
}

// --- router: fp32 logits, top-2, renorm, scatter lists; also emits h_bf ----
__global__ __launch_bounds__(256) void router_kernel(
    const float* __restrict__ h, const float* __restrict__ gw,
    const float* __restrict__ segw,
    unsigned short* __restrict__ h_bf,
    float* __restrict__ sig, int* __restrict__ cnt,
    int* __restrict__ enc, float* __restrict__ wl) {
    int w = threadIdx.x >> 6, l = threadIdx.x & 63;
    int t = blockIdx.x * 4 + w;
    float p[9];
#pragma unroll
    for (int e = 0; e < 9; ++e) p[e] = 0.f;
    const float* hr = h + (size_t)t * DIM;
    unsigned short* hb = h_bf + (size_t)t * DIM;
    for (int i = 0; i < DIM; i += 64) {
        float x = hr[i + l];
        hb[i + l] = f2bf(x);          // fused h cast
#pragma unroll
        for (int e = 0; e < NEXP; ++e) p[e] += x * gw[e * DIM + i + l];
        p[8] += x * segw[i + l];
    }
#pragma unroll
    for (int off = 32; off > 0; off >>= 1) {
#pragma unroll
        for (int e = 0; e < 9; ++e) p[e] += __shfl_xor(p[e], off, 64);
    }
    if (l == 0) {
        int b1 = 0; float v1 = p[0];
        for (int e = 1; e < NEXP; ++e) if (p[e] > v1) { v1 = p[e]; b1 = e; }
        int b2 = -1; float v2 = -1e30f;
        for (int e = 0; e < NEXP; ++e)
            if (e != b1 && p[e] > v2) { v2 = p[e]; b2 = e; }
        float w1 = 1.f / (1.f + __expf(v2 - v1));
        int pos = atomicAdd(&cnt[b1], 1);
        enc[b1 * T_TOK + pos] = 2 * t;     wl[b1 * T_TOK + pos] = w1;
        pos = atomicAdd(&cnt[b2], 1);
        enc[b2 * T_TOK + pos] = 2 * t + 1; wl[b2 * T_TOK + pos] = 1.f - w1;
        sig[t] = 1.f / (1.f + __expf(-p[8]));
    }
}

// ---------------------------------------------------------------------------
// 1-wave 64(M)x256(B-rows) GEMM tile, BK=64, single 40KB LDS buffer.
// LDS: both-sides swizzle LDS[row][slot16B] = G[row][slot ^ (row&7)].
// Stage: 8-row calls; lane l: subrow=l>>3, src chunk = ((l&7)^(l>>3))<<3.
// Read: addr = row*64 + (((kk*4+q)<<3) ^ ((row&7)<<3)) -> 2-way max (free).
// K-step: vmcnt(0) -> kk0 frags -> MFMA64 -> kk1 frags -> lgkmcnt(0) ->
//   issue next 40 gl2lds -> MFMA64.  No s_barrier anywhere.
// ---------------------------------------------------------------------------

// --- merged gate+up GEMM (shared + all experts, 1 wave/block) --------------
// 80 z-slices of 128 out-cols: z<32 shared (gc0=z*128); z>=32: e=(z-32)/6,
// gc0=((z-32)%6)*128. Grid 80*64, decode: xcd=g&7, slot=g>>3,
// z=(slot>>6)*8+xcd, x=slot&63 -> one slice's 64 token-blocks on one XCD.
// B tile 256 rows: rg=row>>4 (0..15); even rg gate / odd rg up, 16-col span
// gc0+16*(rg>>1) -> silu pairs acc[i][2m],acc[i][2m+1], m=0..7.
__global__ __launch_bounds__(64, 1) void gemm_gateup_all(
    const unsigned short* __restrict__ hA,
    const unsigned short* __restrict__ wsg, const unsigned short* __restrict__ wsu,
    const unsigned short* __restrict__ wgu,
    const int* __restrict__ enc, const int* __restrict__ cnt_arr,
    unsigned short* __restrict__ act_s, unsigned short* __restrict__ act_e) {
    unsigned g = blockIdx.x;
    unsigned xcd = g & 7, slot = g >> 3;
    unsigned z = (slot >> 6) * 8 + xcd;       // 0..79
    unsigned x = slot & 63;

    const unsigned short *Wg, *Wu;
    const int* lst; int cnt, gc0, ldo;
    unsigned short* outp;
    if (z < 32) {
        gc0 = z * 128; Wg = wsg; Wu = wsu;
        lst = nullptr; cnt = T_TOK; outp = act_s; ldo = ISHR;
    } else {
        int zz = z - 32;
        int e = zz / 6, ny = zz % 6;
        gc0 = ny * 128;
        Wg = wgu + (size_t)e * 2 * IEXP * DIM;
        Wu = Wg + (size_t)IEXP * DIM;
        lst = enc + e * T_TOK; cnt = cnt_arr[e];
        outp = act_e + (size_t)e * T_TOK * IEXP; ldo = IEXP;
    }
    int m0 = x * 64;
    if (m0 >= cnt) return;

    __shared__ __align__(16) unsigned short As[64 * 64];    //  8 KB
    __shared__ __align__(16) unsigned short Bs[256 * 64];   // 32 KB

    int l = threadIdx.x;                 // 0..63
    int subrow = l >> 3;
    int chunk8 = ((l & 7) ^ subrow) << 3;  // swizzled src chunk, elem units

    unsigned aoff[8];
#pragma unroll
    for (int c = 0; c < 8; ++c) {
        int row = 8 * c + subrow;        // A tile row 0..63
        int pp = m0 + row; if (pp >= cnt) pp = cnt - 1;
        int tk = lst ? (lst[pp] >> 1) : pp;
        aoff[c] = (unsigned)(tk * DIM + chunk8);
    }
    unsigned boff[32];
#pragma unroll
    for (int c = 0; c < 32; ++c) {
        // B row 8c+subrow; rg=c>>1; parity=(c>>1)&1; span=c>>2
        int wrow = gc0 + 16 * (c >> 2) + 8 * (c & 1) + subrow;
        boff[c] = (unsigned)(wrow * DIM + chunk8);
    }

    f32x4_t zero4 = {0.f, 0.f, 0.f, 0.f};
    f32x4_t acc[4][16];
#pragma unroll
    for (int i = 0; i < 4; ++i)
#pragma unroll
        for (int j = 0; j < 16; ++j) acc[i][j] = zero4;

    int lane15 = l & 15, q = l >> 4;
    int sx = (lane15 & 7) << 3;
    int cxk0 = (q << 3) ^ sx;            // kk=0 read slot
    int cxk1 = ((4 + q) << 3) ^ sx;      // kk=1 read slot

    // stage tile 0
#pragma unroll
    for (int c = 0; c < 8; ++c) gl2lds16(hA + aoff[c], &As[c * 512]);
#pragma unroll
    for (int c = 0; c < 32; ++c)
        gl2lds16((((c >> 1) & 1) ? Wu : Wg) + boff[c], &Bs[c * 512]);

    const int NK = DIM / 64;             // 32
    for (int t = 0; t < NK; ++t) {
        asm volatile("s_waitcnt vmcnt(0)" ::: "memory");
        __builtin_amdgcn_sched_barrier(0);
#pragma unroll
        for (int kk = 0; kk < 2; ++kk) {
            int cx = kk ? cxk1 : cxk0;
            bf16x8_t a[4], b[16];
#pragma unroll
            for (int i = 0; i < 4; ++i)
                a[i] = *(const bf16x8_t*)&As[1024 * i + lane15 * 64 + cx];
#pragma unroll
            for (int j = 0; j < 16; ++j)
                b[j] = *(const bf16x8_t*)&Bs[1024 * j + lane15 * 64 + cx];
            if (kk == 1) {
                asm volatile("s_waitcnt lgkmcnt(0)" ::: "memory");
                __builtin_amdgcn_sched_barrier(0);
                if (t + 1 < NK) {        // LDS free: issue next tile
                    int k1 = (t + 1) * 64;
#pragma unroll
                    for (int c = 0; c < 8; ++c)
                        gl2lds16(hA + aoff[c] + k1, &As[c * 512]);
#pragma unroll
                    for (int c = 0; c < 32; ++c)
                        gl2lds16((((c >> 1) & 1) ? Wu : Wg) + boff[c] + k1,
                                 &Bs[c * 512]);
                }
                __builtin_amdgcn_sched_barrier(0);
            }
            __builtin_amdgcn_s_setprio(1);
#pragma unroll
            for (int i = 0; i < 4; ++i)
#pragma unroll
                for (int j = 0; j < 16; ++j)
                    acc[i][j] = __builtin_amdgcn_mfma_f32_16x16x32_bf16(
                        a[i], b[j], acc[i][j], 0, 0, 0);
            __builtin_amdgcn_s_setprio(0);
        }
    }

#pragma unroll
    for (int i = 0; i < 4; ++i) {
#pragma unroll
        for (int r = 0; r < 4; ++r) {
            int p = m0 + 16 * i + 4 * q + r;      // list position, <4096
            unsigned short* orow = outp + (size_t)p * ldo + gc0 + lane15;
#pragma unroll
            for (int m = 0; m < 8; ++m) {
                float gg = acc[i][2 * m][r];      // gate (even rg)
                float uu = acc[i][2 * m + 1][r];  // up   (odd rg)
                orow[16 * m] = f2bf((gg / (1.f + __expf(-gg))) * uu);
            }
        }
    }
}

// --- shared-expert down GEMM: plain stores, covers every out element -------
// 8 y-panels of 256 cols: grid 8*64, xcd=g&7 -> y=xcd (one panel per XCD:
// 2MB wsd panel L2-resident, act_s streamed ONCE per XCD), x=g>>3.
__global__ __launch_bounds__(64, 1) void gemm_down_shared(
    const unsigned short* __restrict__ act_s,
    const unsigned short* __restrict__ wsd,
    const float* __restrict__ sig,
    float* __restrict__ out) {
    unsigned g = blockIdx.x;
    unsigned y = g & 7;
    unsigned x = g >> 3;
    int m0 = x * 64;
    int n0 = y * 256;

    __shared__ __align__(16) unsigned short As[64 * 64];
    __shared__ __align__(16) unsigned short Bs[256 * 64];

    int l = threadIdx.x;
    int subrow = l >> 3;
    int chunk8 = ((l & 7) ^ subrow) << 3;

    unsigned aoff[8];
#pragma unroll
    for (int c = 0; c < 8; ++c)
        aoff[c] = (unsigned)((m0 + 8 * c + subrow) * ISHR + chunk8);
    unsigned boff[32];
#pragma unroll
    for (int c = 0; c < 32; ++c)
        boff[c] = (unsigned)((n0 + 8 * c + subrow) * ISHR + chunk8);

    f32x4_t zero4 = {0.f, 0.f, 0.f, 0.f};
    f32x4_t acc[4][16];
#pragma unroll
    for (int i = 0; i < 4; ++i)
#pragma unroll
        for (int j = 0; j < 16; ++j) acc[i][j] = zero4;

    int lane15 = l & 15, q = l >> 4;
    int sx = (lane15 & 7) << 3;
    int cxk0 = (q << 3) ^ sx;
    int cxk1 = ((4 + q) << 3) ^ sx;

#pragma unroll
    for (int c = 0; c < 8; ++c) gl2lds16(act_s + aoff[c], &As[c * 512]);
#pragma unroll
    for (int c = 0; c < 32; ++c) gl2lds16(wsd + boff[c], &Bs[c * 512]);

    const int NK = ISHR / 64;            // 64
    for (int t = 0; t < NK; ++t) {
        asm volatile("s_waitcnt vmcnt(0)" ::: "memory");
        __builtin_amdgcn_sched_barrier(0);
#pragma unroll
        for (int kk = 0; kk < 2; ++kk) {
            int cx = kk ? cxk1 : cxk0;
            bf16x8_t a[4], b[16];
#pragma unroll
            for (int i = 0; i < 4; ++i)
                a[i] = *(const bf16x8_t*)&As[1024 * i + lane15 * 64 + cx];
#pragma unroll
            for (int j = 0; j < 16; ++j)
                b[j] = *(const bf16x8_t*)&Bs[1024 * j + lane15 * 64 + cx];
            if (kk == 1) {
                asm volatile("s_waitcnt lgkmcnt(0)" ::: "memory");
                __builtin_amdgcn_sched_barrier(0);
                if (t + 1 < NK) {
                    int k1 = (t + 1) * 64;
#pragma unroll
                    for (int c = 0; c < 8; ++c)
                        gl2lds16(act_s + aoff[c] + k1, &As[c * 512]);
#pragma unroll
                    for (int c = 0; c < 32; ++c)
                        gl2lds16(wsd + boff[c] + k1, &Bs[c * 512]);
                }
                __builtin_amdgcn_sched_barrier(0);
            }
            __builtin_amdgcn_s_setprio(1);
#pragma unroll
            for (int i = 0; i < 4; ++i)
#pragma unroll
                for (int j = 0; j < 16; ++j)
                    acc[i][j] = __builtin_amdgcn_mfma_f32_16x16x32_bf16(
                        a[i], b[j], acc[i][j], 0, 0, 0);
            __builtin_amdgcn_s_setprio(0);
        }
    }

#pragma unroll
    for (int i = 0; i < 4; ++i) {
#pragma unroll
        for (int r = 0; r < 4; ++r) {
            int p = m0 + 16 * i + 4 * q + r;
            float sc = sig[p];
            float* orow = out + (size_t)p * DIM + n0 + lane15;
#pragma unroll
            for (int j = 0; j < 16; ++j)
                orow[16 * j] = sc * acc[i][j][r];
        }
    }
}

// --- expert down GEMM: gathered A rows, atomicAdd into out -----------------
// 64 panels (e=panel>>3, y=panel&7, n0=y*256). Grid 64*64:
// xcd=g&7, slot=g>>3, panel=(slot>>6)*8+xcd, x=slot&63.
__global__ __launch_bounds__(64, 1) void gemm_down_expert(
    const unsigned short* __restrict__ act_e,
    const unsigned short* __restrict__ wdn,
    const int* __restrict__ enc, const int* __restrict__ cnt_arr,
    const float* __restrict__ wlst,
    float* __restrict__ out) {
    unsigned g = blockIdx.x;
    unsigned xcd = g & 7, slot = g >> 3;
    unsigned panel = (slot >> 6) * 8 + xcd;   // 0..63
    unsigned x = slot & 63;
    int e = panel >> 3, y = panel & 7;

    const unsigned short* A = act_e + (size_t)e * T_TOK * IEXP;
    const unsigned short* W = wdn + (size_t)e * DIM * IEXP;
    const int* lst = enc + e * T_TOK;
    const float* scl = wlst + (size_t)e * T_TOK;
    int cnt = cnt_arr[e];
    int m0 = x * 64;
    if (m0 >= cnt) return;
    int n0 = y * 256;

    __shared__ __align__(16) unsigned short As[64 * 64];
    __shared__ __align__(16) unsigned short Bs[256 * 64];

    int l = threadIdx.x;
    int subrow = l >> 3;
    int chunk8 = ((l & 7) ^ subrow) << 3;

    unsigned aoff[8];
#pragma unroll
    for (int c = 0; c < 8; ++c) {
        int pp = m0 + 8 * c + subrow; if (pp >= cnt) pp = cnt - 1;
        aoff[c] = (unsigned)(pp * IEXP + chunk8);
    }
    unsigned boff[32];
#pragma unroll
    for (int c = 0; c < 32; ++c)
        boff[c] = (unsigned)((n0 + 8 * c + subrow) * IEXP + chunk8);

    f32x4_t zero4 = {0.f, 0.f, 0.f, 0.f};
    f32x4_t acc[4][16];
#pragma unroll
    for (int i = 0; i < 4; ++i)
#pragma unroll
        for (int j = 0; j < 16; ++j) acc[i][j] = zero4;

    int lane15 = l & 15, q = l >> 4;
    int sx = (lane15 & 7) << 3;
    int cxk0 = (q << 3) ^ sx;
    int cxk1 = ((4 + q) << 3) ^ sx;

#pragma unroll
    for (int c = 0; c < 8; ++c) gl2lds16(A + aoff[c], &As[c * 512]);
#pragma unroll
    for (int c = 0; c < 32; ++c) gl2lds16(W + boff[c], &Bs[c * 512]);

    const int NK = IEXP / 64;            // 12
    for (int t = 0; t < NK; ++t) {
        asm volatile("s_waitcnt vmcnt(0)" ::: "memory");
        __builtin_amdgcn_sched_barrier(0);
#pragma unroll
        for (int kk = 0; kk < 2; ++kk) {
            int cx = kk ? cxk1 : cxk0;
            bf16x8_t a[4], b[16];
#pragma unroll
            for (int i = 0; i < 4; ++i)
                a[i] = *(const bf16x8_t*)&As[1024 * i + lane15 * 64 + cx];
#pragma unroll
            for (int j = 0; j < 16; ++j)
                b[j] = *(const bf16x8_t*)&Bs[1024 * j + lane15 * 64 + cx];
            if (kk == 1) {
                asm volatile("s_waitcnt lgkmcnt(0)" ::: "memory");
                __builtin_amdgcn_sched_barrier(0);
                if (t + 1 < NK) {
                    int k1 = (t + 1) * 64;
#pragma unroll
                    for (int c = 0; c < 8; ++c)
                        gl2lds16(A + aoff[c] + k1, &As[c * 512]);
#pragma unroll
                    for (int c = 0; c < 32; ++c)
                        gl2lds16(W + boff[c] + k1, &Bs[c * 512]);
                }
                __builtin_amdgcn_sched_barrier(0);
            }
            __builtin_amdgcn_s_setprio(1);
#pragma unroll
            for (int i = 0; i < 4; ++i)
#pragma unroll
                for (int j = 0; j < 16; ++j)
                    acc[i][j] = __builtin_amdgcn_mfma_f32_16x16x32_bf16(
                        a[i], b[j], acc[i][j], 0, 0, 0);
            __builtin_amdgcn_s_setprio(0);
        }
    }

#pragma unroll
    for (int i = 0; i < 4; ++i) {
#pragma unroll
        for (int r = 0; r < 4; ++r) {
            int p = m0 + 16 * i + 4 * q + r;
            if (p < cnt) {
                int dest = lst[p] >> 1;
                float sc = scl[p];
                float* orow = out + (size_t)dest * DIM + n0 + lane15;
#pragma unroll
                for (int j = 0; j < 16; ++j)
                    atomicAdd(&orow[16 * j], sc * acc[i][j][r]);
            }
        }
    }
}

extern "C" void kernel_launch(void* const* d_in, const int* in_sizes, int n_in,
                              void* d_out, int out_size, void* d_ws, size_t ws_size,
                              hipStream_t stream) {
    (void)in_sizes; (void)n_in; (void)out_size; (void)ws_size;
    const float* h    = (const float*)d_in[0];  // [2,2048,2048]
    const float* gw   = (const float*)d_in[1];  // [8,2048]
    const float* gup  = (const float*)d_in[2];  // [8,1536,2048]
    const float* dnp  = (const float*)d_in[3];  // [8,2048,768]
    const float* sgw  = (const float*)d_in[4];  // [4096,2048]
    const float* suw  = (const float*)d_in[5];  // [4096,2048]
    const float* sdw  = (const float*)d_in[6];  // [2048,4096]
    const float* segw = (const float*)d_in[7];  // [1,2048]
    float* out = (float*)d_out;

    char* ws = (char*)d_ws;
    size_t off = 0;
    auto alloc = [&](size_t bytes) {
        void* p = ws + off;
        off += (bytes + 255) & ~(size_t)255;
        return p;
    };
    unsigned short* h_bf   = (unsigned short*)alloc((size_t)T_TOK * DIM * 2);
    unsigned short* wgu_bf = (unsigned short*)alloc((size_t)NEXP * 2 * IEXP * DIM * 2);
    unsigned short* wdn_bf = (unsigned short*)alloc((size_t)NEXP * DIM * IEXP * 2);
    unsigned short* wsg_bf = (unsigned short*)alloc((size_t)ISHR * DIM * 2);
    unsigned short* wsu_bf = (unsigned short*)alloc((size_t)ISHR * DIM * 2);
    unsigned short* wsd_bf = (unsigned short*)alloc((size_t)DIM * ISHR * 2);
    unsigned short* act_s  = (unsigned short*)alloc((size_t)T_TOK * ISHR * 2);
    unsigned short* act_e  = (unsigned short*)alloc((size_t)NEXP * T_TOK * IEXP * 2);
    float* sig     = (float*)alloc((size_t)T_TOK * 4);
    int*   cnt     = (int*)alloc(NEXP * 4);
    int*   enc     = (int*)alloc((size_t)NEXP * T_TOK * 4);
    float* wl      = (float*)alloc((size_t)NEXP * T_TOK * 4);

    // 1. fused weight casts + cnt zero
    fused_cast_kernel<<<C4 / 256, 256, 0, stream>>>(
        gup, dnp, sgw, suw, sdw,
        wgu_bf, wdn_bf, wsg_bf, wsu_bf, wsd_bf, cnt);

    // 2. router (fp32 logits; also emits h_bf)
    router_kernel<<<T_TOK / 4, 256, 0, stream>>>(
        h, gw, segw, h_bf, sig, cnt, enc, wl);

    // 3. all gate+up GEMMs, 1-wave blocks, XCD-swizzled 1-D grid (80 z * 64 x)
    gemm_gateup_all<<<80 * 64, 64, 0, stream>>>(
        h_bf, wsg_bf, wsu_bf, wgu_bf, enc, cnt, act_s, act_e);

    // 4. shared down: plain stores, one 256-col panel per XCD (8 y * 64 x)
    gemm_down_shared<<<8 * 64, 64, 0, stream>>>(
        act_s, wsd_bf, sig, out);

    // 5. expert down: atomicAdd on top, stream-ordered (64 panels * 64 x)
    gemm_down_expert<<<64 * 64, 64, 0, stream>>>(
        act_e, wdn_bf, enc, cnt, wl, out);
}

// Round 5
// 750.692 us; speedup vs baseline: 4.2744x; 4.2744x over previous
//
#include <hip/hip_runtime.h>

// ---------------------------------------------------------------------------
// EPSparseMoeBlock: B=2, L=2048, D=2048, E=8, K=2, I=768, IS=4096, T=4096
// bf16 MFMA GEMMs (fp32 accum), fp32 router, sparse top-2 dispatch.
// R9 (proven 755us): 1-wave 64x128 barrier-free tiles, acc[4][8],
//   __launch_bounds__(64,2), XCD-aware decode, setprio. gateup 233us @37%.
// R10 FAILED: N=256/acc[4][16] spilled (VGPR 256, WRITE 276MB scratch) ->
//   1607us. Reverted all shapes to R9.
// R11: eliminate down_expert's 67M global fp32 atomicAdds (est ~300-450us of
//   R9's ~450us down budget). down_expert now STORES w*acc (f32) into
//   compact dnout[slot][D] (slot=enc value 2t/2t+1, 8192 rows, 67MB);
//   down_shared (launched after) fuses combine:
//   out[t] = sig*accS + dnout[2t] + dnout[2t+1].  No atomics anywhere.
// 5 launches: cast -> router(+h cast) -> gateup_all -> down_expert -> down_shared
// ---------------------------------------------------------------------------

#define T_TOK 4096
#define DIM   2048
#define NEXP  8
#define IEXP  768
#define ISHR  4096

typedef __attribute__((ext_vector_type(8))) short bf16x8_t;  // 8 bf16 (4 VGPR)
typedef __attribute__((ext_vector_type(4))) float f32x4_t;   // MFMA acc

__device__ __forceinline__ unsigned short f2bf(float f) {
    unsigned int u = __float_as_uint(f);
    u += 0x7fffu + ((u >> 16) & 1u);   // round-to-nearest-even
    return (unsigned short)(u >> 16);
}

// async global->LDS, 16 B per lane; lds dest is wave-uniform base,
// HW scatters lane i at base + i*16 (m97/m104 semantics).
__device__ __forceinline__ void gl2lds16(const unsigned short* g, unsigned short* l) {
    __builtin_amdgcn_global_load_lds(
        (const __attribute__((address_space(1))) unsigned int*)g,
        (__attribute__((address_space(3))) unsigned int*)l, 16, 0, 0);
}

// --- fused weight casts fp32 -> bf16 (5 tensors) + cnt zero ----------------
#define C0 6291456   // gup   (8*1536*2048)/4
#define C1 9437184   // + dnp (8*2048*768)/4
#define C2 11534336  // + sgw (4096*2048)/4
#define C3 13631488  // + suw
#define C4 15728640  // + sdw
__global__ __launch_bounds__(256) void fused_cast_kernel(
    const float* __restrict__ s0, const float* __restrict__ s1,
    const float* __restrict__ s2, const float* __restrict__ s3,
    const float* __restrict__ s4,
    unsigned short* __restrict__ d0, unsigned short* __restrict__ d1,
    unsigned short* __restrict__ d2, unsigned short* __restrict__ d3,
    unsigned short* __restrict__ d4, int* __restrict__ cnt) {
    if (blockIdx.x == 0 && threadIdx.x < NEXP) cnt[threadIdx.x] = 0;
    int i = blockIdx.x * 256 + threadIdx.x;
    const float* src; unsigned short* dst; int base;
    if      (i < C0) { src = s0; dst = d0; base = 0;  }
    else if (i < C1) { src = s1; dst = d1; base = C0; }
    else if (i < C2) { src = s2; dst = d2; base = C1; }
    else if (i < C3) { src = s3; dst = d3; base = C2; }
    else             { src = s4; dst = d4; base = C3; }
    int j = i - base;
    float4 v = ((const float4*)src)[j];
    short4 r;
    r.x = (short)f2bf(v.x); r.y = (short)f2bf(v.y);
    r.z = (short)f2bf(v.z); r.w = (short)f2bf(v.w);
    ((short4*)dst)[j] = r;
}

// --- router: fp32 logits, top-2, renorm, scatter lists; also emits h_bf ----
__global__ __launch_bounds__(256) void router_kernel(
    const float* __restrict__ h, const float* __restrict__ gw,
    const float* __restrict__ segw,
    unsigned short* __restrict__ h_bf,
    float* __restrict__ sig, int* __restrict__ cnt,
    int* __restrict__ enc, float* __restrict__ wl) {
    int w = threadIdx.x >> 6, l = threadIdx.x & 63;
    int t = blockIdx.x * 4 + w;
    float p[9];
#pragma unroll
    for (int e = 0; e < 9; ++e) p[e] = 0.f;
    const float* hr = h + (size_t)t * DIM;
    unsigned short* hb = h_bf + (size_t)t * DIM;
    for (int i = 0; i < DIM; i += 64) {
        float x = hr[i + l];
        hb[i + l] = f2bf(x);          // fused h cast
#pragma unroll
        for (int e = 0; e < NEXP; ++e) p[e] += x * gw[e * DIM + i + l];
        p[8] += x * segw[i + l];
    }
#pragma unroll
    for (int off = 32; off > 0; off >>= 1) {
#pragma unroll
        for (int e = 0; e < 9; ++e) p[e] += __shfl_xor(p[e], off, 64);
    }
    if (l == 0) {
        int b1 = 0; float v1 = p[0];
        for (int e = 1; e < NEXP; ++e) if (p[e] > v1) { v1 = p[e]; b1 = e; }
        int b2 = -1; float v2 = -1e30f;
        for (int e = 0; e < NEXP; ++e)
            if (e != b1 && p[e] > v2) { v2 = p[e]; b2 = e; }
        float w1 = 1.f / (1.f + __expf(v2 - v1));
        int pos = atomicAdd(&cnt[b1], 1);
        enc[b1 * T_TOK + pos] = 2 * t;     wl[b1 * T_TOK + pos] = w1;
        pos = atomicAdd(&cnt[b2], 1);
        enc[b2 * T_TOK + pos] = 2 * t + 1; wl[b2 * T_TOK + pos] = 1.f - w1;
        sig[t] = 1.f / (1.f + __expf(-p[8]));
    }
}

// ---------------------------------------------------------------------------
// 1-wave 64(M)x128(B-rows) GEMM tile, BK=64, single 24KB LDS buffer (R9).
// LDS: both-sides swizzle LDS[row][slot16B] = G[row][slot ^ (row&7)].
// Stage: 8-row calls; lane l: subrow=l>>3, src chunk = ((l&7)^(l>>3))<<3.
// Read: addr = row*64 + (((kk*4+q)<<3) ^ ((row&7)<<3)) -> 2-way max (free).
// K-step: vmcnt(0) -> kk0 frags -> MFMA32 -> kk1 frags -> lgkmcnt(0) ->
//   issue next 24 gl2lds -> MFMA32.  No s_barrier anywhere.
// ---------------------------------------------------------------------------

// --- merged gate+up GEMM (shared + all experts, 1 wave/block) --------------
// 1-D grid 160*64; XCD decode: xcd=g&7, slot=g>>3, z=(slot>>6)*8+xcd, x=slot&63
// z<64: shared, gc0=z*64. z>=64: e=(z-64)/12, gc0=((z-64)%12)*64.
// B tile 128 rows: rg=row>>4 (0..7); even rg gate / odd rg up, span
// gc0+16*(rg>>1); silu pairs acc[i][2m],acc[i][2m+1].
__global__ __launch_bounds__(64, 2) void gemm_gateup_all(
    const unsigned short* __restrict__ hA,
    const unsigned short* __restrict__ wsg, const unsigned short* __restrict__ wsu,
    const unsigned short* __restrict__ wgu,
    const int* __restrict__ enc, const int* __restrict__ cnt_arr,
    unsigned short* __restrict__ act_s, unsigned short* __restrict__ act_e) {
    unsigned g = blockIdx.x;
    unsigned xcd = g & 7, slot = g >> 3;
    unsigned z = (slot >> 6) * 8 + xcd;       // 0..159
    unsigned x = slot & 63;

    const unsigned short *Wg, *Wu;
    const int* lst; int cnt, gc0, ldo;
    unsigned short* outp;
    if (z < 64) {
        gc0 = z * 64; Wg = wsg; Wu = wsu;
        lst = nullptr; cnt = T_TOK; outp = act_s; ldo = ISHR;
    } else {
        int zz = z - 64;
        int e = zz / 12, ny = zz % 12;
        gc0 = ny * 64;
        Wg = wgu + (size_t)e * 2 * IEXP * DIM;
        Wu = Wg + (size_t)IEXP * DIM;
        lst = enc + e * T_TOK; cnt = cnt_arr[e];
        outp = act_e + (size_t)e * T_TOK * IEXP; ldo = IEXP;
    }
    int m0 = x * 64;
    if (m0 >= cnt) return;

    __shared__ __align__(16) unsigned short As[64 * 64];    //  8 KB
    __shared__ __align__(16) unsigned short Bs[128 * 64];   // 16 KB

    int l = threadIdx.x;                 // 0..63
    int subrow = l >> 3;
    int chunk8 = ((l & 7) ^ subrow) << 3;  // swizzled src chunk, elem units

    unsigned aoff[8];
#pragma unroll
    for (int c = 0; c < 8; ++c) {
        int row = 8 * c + subrow;        // A tile row 0..63
        int pp = m0 + row; if (pp >= cnt) pp = cnt - 1;
        int tk = lst ? (lst[pp] >> 1) : pp;
        aoff[c] = (unsigned)(tk * DIM + chunk8);
    }
    unsigned boff[16];
#pragma unroll
    for (int c = 0; c < 16; ++c) {
        // B tile row 8c+subrow; rg=c>>1; parity=(c>>1)&1; span=gc0+16*(c>>2)
        int wrow = gc0 + 16 * (c >> 2) + 8 * (c & 1) + subrow;
        boff[c] = (unsigned)(wrow * DIM + chunk8);
    }

    f32x4_t zero4 = {0.f, 0.f, 0.f, 0.f};
    f32x4_t acc[4][8];
#pragma unroll
    for (int i = 0; i < 4; ++i)
#pragma unroll
        for (int j = 0; j < 8; ++j) acc[i][j] = zero4;

    int lane15 = l & 15, q = l >> 4;
    int sx = (lane15 & 7) << 3;
    int cxk0 = (q << 3) ^ sx;            // kk=0 read slot
    int cxk1 = ((4 + q) << 3) ^ sx;      // kk=1 read slot

    // stage tile 0
#pragma unroll
    for (int c = 0; c < 8; ++c) gl2lds16(hA + aoff[c], &As[c * 512]);
#pragma unroll
    for (int c = 0; c < 16; ++c)
        gl2lds16((((c >> 1) & 1) ? Wu : Wg) + boff[c], &Bs[c * 512]);

    const int NK = DIM / 64;             // 32
    for (int t = 0; t < NK; ++t) {
        asm volatile("s_waitcnt vmcnt(0)" ::: "memory");
        __builtin_amdgcn_sched_barrier(0);
#pragma unroll
        for (int kk = 0; kk < 2; ++kk) {
            int cx = kk ? cxk1 : cxk0;
            bf16x8_t a[4], b[8];
#pragma unroll
            for (int i = 0; i < 4; ++i)
                a[i] = *(const bf16x8_t*)&As[1024 * i + lane15 * 64 + cx];
#pragma unroll
            for (int j = 0; j < 8; ++j)
                b[j] = *(const bf16x8_t*)&Bs[1024 * j + lane15 * 64 + cx];
            if (kk == 1) {
                asm volatile("s_waitcnt lgkmcnt(0)" ::: "memory");
                __builtin_amdgcn_sched_barrier(0);
                if (t + 1 < NK) {        // LDS free: issue next tile
                    int k1 = (t + 1) * 64;
#pragma unroll
                    for (int c = 0; c < 8; ++c)
                        gl2lds16(hA + aoff[c] + k1, &As[c * 512]);
#pragma unroll
                    for (int c = 0; c < 16; ++c)
                        gl2lds16((((c >> 1) & 1) ? Wu : Wg) + boff[c] + k1,
                                 &Bs[c * 512]);
                }
                __builtin_amdgcn_sched_barrier(0);
            }
            __builtin_amdgcn_s_setprio(1);
#pragma unroll
            for (int i = 0; i < 4; ++i)
#pragma unroll
                for (int j = 0; j < 8; ++j)
                    acc[i][j] = __builtin_amdgcn_mfma_f32_16x16x32_bf16(
                        a[i], b[j], acc[i][j], 0, 0, 0);
            __builtin_amdgcn_s_setprio(0);
        }
    }

#pragma unroll
    for (int i = 0; i < 4; ++i) {
#pragma unroll
        for (int r = 0; r < 4; ++r) {
            int p = m0 + 16 * i + 4 * q + r;      // list position, <4096
            unsigned short* orow = outp + (size_t)p * ldo + gc0 + lane15;
#pragma unroll
            for (int m = 0; m < 4; ++m) {
                float gg = acc[i][2 * m][r];      // gate (even rg)
                float uu = acc[i][2 * m + 1][r];  // up   (odd rg)
                orow[16 * m] = f2bf((gg / (1.f + __expf(-gg))) * uu);
            }
        }
    }
}

// --- expert down GEMM: gathered A rows, STORES w*acc into dnout ------------
// dnout[slot][DIM] f32, slot = enc value (2t or 2t+1), 8192 rows compact.
// 1-D grid 128*64; xcd=g&7, slot=g>>3, panel=(slot>>6)*8+xcd (0..127),
// e=panel>>4, y=panel&15, x=slot&63.  No atomics (R11).
__global__ __launch_bounds__(64, 2) void gemm_down_expert(
    const unsigned short* __restrict__ act_e,
    const unsigned short* __restrict__ wdn,
    const int* __restrict__ enc, const int* __restrict__ cnt_arr,
    const float* __restrict__ wlst,
    float* __restrict__ dnout) {
    unsigned g = blockIdx.x;
    unsigned xcd = g & 7, slotg = g >> 3;
    unsigned panel = (slotg >> 6) * 8 + xcd;  // 0..127
    unsigned x = slotg & 63;
    int e = panel >> 4, y = panel & 15;

    const unsigned short* A = act_e + (size_t)e * T_TOK * IEXP;
    const unsigned short* W = wdn + (size_t)e * DIM * IEXP;
    const int* lst = enc + e * T_TOK;
    const float* scl = wlst + (size_t)e * T_TOK;
    int cnt = cnt_arr[e];
    int m0 = x * 64;
    if (m0 >= cnt) return;
    int n0 = y * 128;

    __shared__ __align__(16) unsigned short As[64 * 64];
    __shared__ __align__(16) unsigned short Bs[128 * 64];

    int l = threadIdx.x;
    int subrow = l >> 3;
    int chunk8 = ((l & 7) ^ subrow) << 3;

    unsigned aoff[8];
#pragma unroll
    for (int c = 0; c < 8; ++c) {
        int pp = m0 + 8 * c + subrow; if (pp >= cnt) pp = cnt - 1;
        aoff[c] = (unsigned)(pp * IEXP + chunk8);
    }
    unsigned boff[16];
#pragma unroll
    for (int c = 0; c < 16; ++c)
        boff[c] = (unsigned)((n0 + 8 * c + subrow) * IEXP + chunk8);

    f32x4_t zero4 = {0.f, 0.f, 0.f, 0.f};
    f32x4_t acc[4][8];
#pragma unroll
    for (int i = 0; i < 4; ++i)
#pragma unroll
        for (int j = 0; j < 8; ++j) acc[i][j] = zero4;

    int lane15 = l & 15, q = l >> 4;
    int sx = (lane15 & 7) << 3;
    int cxk0 = (q << 3) ^ sx;
    int cxk1 = ((4 + q) << 3) ^ sx;

#pragma unroll
    for (int c = 0; c < 8; ++c) gl2lds16(A + aoff[c], &As[c * 512]);
#pragma unroll
    for (int c = 0; c < 16; ++c) gl2lds16(W + boff[c], &Bs[c * 512]);

    const int NK = IEXP / 64;            // 12
    for (int t = 0; t < NK; ++t) {
        asm volatile("s_waitcnt vmcnt(0)" ::: "memory");
        __builtin_amdgcn_sched_barrier(0);
#pragma unroll
        for (int kk = 0; kk < 2; ++kk) {
            int cx = kk ? cxk1 : cxk0;
            bf16x8_t a[4], b[8];
#pragma unroll
            for (int i = 0; i < 4; ++i)
                a[i] = *(const bf16x8_t*)&As[1024 * i + lane15 * 64 + cx];
#pragma unroll
            for (int j = 0; j < 8; ++j)
                b[j] = *(const bf16x8_t*)&Bs[1024 * j + lane15 * 64 + cx];
            if (kk == 1) {
                asm volatile("s_waitcnt lgkmcnt(0)" ::: "memory");
                __builtin_amdgcn_sched_barrier(0);
                if (t + 1 < NK) {
                    int k1 = (t + 1) * 64;
#pragma unroll
                    for (int c = 0; c < 8; ++c)
                        gl2lds16(A + aoff[c] + k1, &As[c * 512]);
#pragma unroll
                    for (int c = 0; c < 16; ++c)
                        gl2lds16(W + boff[c] + k1, &Bs[c * 512]);
                }
                __builtin_amdgcn_sched_barrier(0);
            }
            __builtin_amdgcn_s_setprio(1);
#pragma unroll
            for (int i = 0; i < 4; ++i)
#pragma unroll
                for (int j = 0; j < 8; ++j)
                    acc[i][j] = __builtin_amdgcn_mfma_f32_16x16x32_bf16(
                        a[i], b[j], acc[i][j], 0, 0, 0);
            __builtin_amdgcn_s_setprio(0);
        }
    }

#pragma unroll
    for (int i = 0; i < 4; ++i) {
#pragma unroll
        for (int r = 0; r < 4; ++r) {
            int p = m0 + 16 * i + 4 * q + r;
            if (p < cnt) {
                int dslot = lst[p];               // 2t or 2t+1, 0..8191
                float sc = scl[p];
                float* drow = dnout + (size_t)dslot * DIM + n0 + lane15;
#pragma unroll
                for (int j = 0; j < 8; ++j)
                    drow[16 * j] = sc * acc[i][j][r];
            }
        }
    }
}

// --- shared-expert down GEMM + final combine (R11) -------------------------
// out[t] = sig[t]*accS + dnout[2t] + dnout[2t+1].  Plain stores, covers all.
// 1-D grid 16*64; xcd=g&7, slot=g>>3, y=(slot>>6)*8+xcd (0..15), x=slot&63.
__global__ __launch_bounds__(64, 2) void gemm_down_shared(
    const unsigned short* __restrict__ act_s,
    const unsigned short* __restrict__ wsd,
    const float* __restrict__ sig,
    const float* __restrict__ dnout,
    float* __restrict__ out) {
    unsigned g = blockIdx.x;
    unsigned xcd = g & 7, slot = g >> 3;
    unsigned y = (slot >> 6) * 8 + xcd;       // 0..15
    unsigned x = slot & 63;
    int m0 = x * 64;
    int n0 = y * 128;

    __shared__ __align__(16) unsigned short As[64 * 64];
    __shared__ __align__(16) unsigned short Bs[128 * 64];

    int l = threadIdx.x;
    int subrow = l >> 3;
    int chunk8 = ((l & 7) ^ subrow) << 3;

    unsigned aoff[8];
#pragma unroll
    for (int c = 0; c < 8; ++c)
        aoff[c] = (unsigned)((m0 + 8 * c + subrow) * ISHR + chunk8);
    unsigned boff[16];
#pragma unroll
    for (int c = 0; c < 16; ++c)
        boff[c] = (unsigned)((n0 + 8 * c + subrow) * ISHR + chunk8);

    f32x4_t zero4 = {0.f, 0.f, 0.f, 0.f};
    f32x4_t acc[4][8];
#pragma unroll
    for (int i = 0; i < 4; ++i)
#pragma unroll
        for (int j = 0; j < 8; ++j) acc[i][j] = zero4;

    int lane15 = l & 15, q = l >> 4;
    int sx = (lane15 & 7) << 3;
    int cxk0 = (q << 3) ^ sx;
    int cxk1 = ((4 + q) << 3) ^ sx;

#pragma unroll
    for (int c = 0; c < 8; ++c) gl2lds16(act_s + aoff[c], &As[c * 512]);
#pragma unroll
    for (int c = 0; c < 16; ++c) gl2lds16(wsd + boff[c], &Bs[c * 512]);

    const int NK = ISHR / 64;            // 64
    for (int t = 0; t < NK; ++t) {
        asm volatile("s_waitcnt vmcnt(0)" ::: "memory");
        __builtin_amdgcn_sched_barrier(0);
#pragma unroll
        for (int kk = 0; kk < 2; ++kk) {
            int cx = kk ? cxk1 : cxk0;
            bf16x8_t a[4], b[8];
#pragma unroll
            for (int i = 0; i < 4; ++i)
                a[i] = *(const bf16x8_t*)&As[1024 * i + lane15 * 64 + cx];
#pragma unroll
            for (int j = 0; j < 8; ++j)
                b[j] = *(const bf16x8_t*)&Bs[1024 * j + lane15 * 64 + cx];
            if (kk == 1) {
                asm volatile("s_waitcnt lgkmcnt(0)" ::: "memory");
                __builtin_amdgcn_sched_barrier(0);
                if (t + 1 < NK) {
                    int k1 = (t + 1) * 64;
#pragma unroll
                    for (int c = 0; c < 8; ++c)
                        gl2lds16(act_s + aoff[c] + k1, &As[c * 512]);
#pragma unroll
                    for (int c = 0; c < 16; ++c)
                        gl2lds16(wsd + boff[c] + k1, &Bs[c * 512]);
                }
                __builtin_amdgcn_sched_barrier(0);
            }
            __builtin_amdgcn_s_setprio(1);
#pragma unroll
            for (int i = 0; i < 4; ++i)
#pragma unroll
                for (int j = 0; j < 8; ++j)
                    acc[i][j] = __builtin_amdgcn_mfma_f32_16x16x32_bf16(
                        a[i], b[j], acc[i][j], 0, 0, 0);
            __builtin_amdgcn_s_setprio(0);
        }
    }

#pragma unroll
    for (int i = 0; i < 4; ++i) {
#pragma unroll
        for (int r = 0; r < 4; ++r) {
            int p = m0 + 16 * i + 4 * q + r;           // token id
            float sc = sig[p];
            const float* d0 = dnout + (size_t)(2 * p) * DIM + n0 + lane15;
            const float* d1 = dnout + (size_t)(2 * p + 1) * DIM + n0 + lane15;
            float* orow = out + (size_t)p * DIM + n0 + lane15;
#pragma unroll
            for (int j = 0; j < 8; ++j)
                orow[16 * j] = sc * acc[i][j][r] + d0[16 * j] + d1[16 * j];
        }
    }
}

extern "C" void kernel_launch(void* const* d_in, const int* in_sizes, int n_in,
                              void* d_out, int out_size, void* d_ws, size_t ws_size,
                              hipStream_t stream) {
    (void)in_sizes; (void)n_in; (void)out_size; (void)ws_size;
    const float* h    = (const float*)d_in[0];  // [2,2048,2048]
    const float* gw   = (const float*)d_in[1];  // [8,2048]
    const float* gup  = (const float*)d_in[2];  // [8,1536,2048]
    const float* dnp  = (const float*)d_in[3];  // [8,2048,768]
    const float* sgw  = (const float*)d_in[4];  // [4096,2048]
    const float* suw  = (const float*)d_in[5];  // [4096,2048]
    const float* sdw  = (const float*)d_in[6];  // [2048,4096]
    const float* segw = (const float*)d_in[7];  // [1,2048]
    float* out = (float*)d_out;

    char* ws = (char*)d_ws;
    size_t off = 0;
    auto alloc = [&](size_t bytes) {
        void* p = ws + off;
        off += (bytes + 255) & ~(size_t)255;
        return p;
    };
    unsigned short* h_bf   = (unsigned short*)alloc((size_t)T_TOK * DIM * 2);
    unsigned short* wgu_bf = (unsigned short*)alloc((size_t)NEXP * 2 * IEXP * DIM * 2);
    unsigned short* wdn_bf = (unsigned short*)alloc((size_t)NEXP * DIM * IEXP * 2);
    unsigned short* wsg_bf = (unsigned short*)alloc((size_t)ISHR * DIM * 2);
    unsigned short* wsu_bf = (unsigned short*)alloc((size_t)ISHR * DIM * 2);
    unsigned short* wsd_bf = (unsigned short*)alloc((size_t)DIM * ISHR * 2);
    unsigned short* act_s  = (unsigned short*)alloc((size_t)T_TOK * ISHR * 2);
    unsigned short* act_e  = (unsigned short*)alloc((size_t)NEXP * T_TOK * IEXP * 2);
    float* dnout   = (float*)alloc((size_t)2 * T_TOK * DIM * 4);   // 67 MB
    float* sig     = (float*)alloc((size_t)T_TOK * 4);
    int*   cnt     = (int*)alloc(NEXP * 4);
    int*   enc     = (int*)alloc((size_t)NEXP * T_TOK * 4);
    float* wl      = (float*)alloc((size_t)NEXP * T_TOK * 4);

    // 1. fused weight casts + cnt zero
    fused_cast_kernel<<<C4 / 256, 256, 0, stream>>>(
        gup, dnp, sgw, suw, sdw,
        wgu_bf, wdn_bf, wsg_bf, wsu_bf, wsd_bf, cnt);

    // 2. router (fp32 logits; also emits h_bf)
    router_kernel<<<T_TOK / 4, 256, 0, stream>>>(
        h, gw, segw, h_bf, sig, cnt, enc, wl);

    // 3. all gate+up GEMMs, 1-wave blocks, XCD-swizzled 1-D grid (160 z * 64 x)
    gemm_gateup_all<<<160 * 64, 64, 0, stream>>>(
        h_bf, wsg_bf, wsu_bf, wgu_bf, enc, cnt, act_s, act_e);

    // 4. expert down: plain stores into compact dnout (128 panels * 64 x)
    gemm_down_expert<<<128 * 64, 64, 0, stream>>>(
        act_e, wdn_bf, enc, cnt, wl, dnout);

    // 5. shared down + combine: out = sig*accS + dnout[2t] + dnout[2t+1]
    gemm_down_shared<<<16 * 64, 64, 0, stream>>>(
        act_s, wsd_bf, sig, dnout, out);
}